// Round 2
// baseline (710.982 us; speedup 1.0000x reference)
//
#include <hip/hip_runtime.h>
#include <cstdint>

typedef __attribute__((ext_vector_type(8)))  short bf16x8;   // 8 x bf16 (4 VGPR)
typedef __attribute__((ext_vector_type(16))) float f32x16;   // MFMA 32x32 acc
typedef __attribute__((ext_vector_type(4)))  int   i32x4;

__device__ __forceinline__ unsigned short f2bf(float x) {    // RNE fp32->bf16
  unsigned u = __float_as_uint(x);
  u += 0x7fffu + ((u >> 16) & 1u);
  return (unsigned short)(u >> 16);
}
__device__ __forceinline__ unsigned pk2bf(float lo, float hi) {
#if defined(__has_builtin)
#if __has_builtin(__builtin_amdgcn_cvt_pk_bf16_f32)
  auto v = __builtin_amdgcn_cvt_pk_bf16_f32(lo, hi);
  unsigned u; __builtin_memcpy(&u, &v, 4); return u;
#else
  return ((unsigned)f2bf(hi) << 16) | (unsigned)f2bf(lo);
#endif
#else
  return ((unsigned)f2bf(hi) << 16) | (unsigned)f2bf(lo);
#endif
}
__device__ __forceinline__ float silu_f(float v) {
  return v * __builtin_amdgcn_rcpf(1.0f + __expf(-v));
}

// ---- pack W0/W1/W2 into MFMA B-frag order via LDS transpose (coalesced R+W).
// dest layout: [layer][g(64 cols)][t(32-col tile)][kt][lane][8], K0 padded 134->144.
// (unchanged from previous verified kernel)
__global__ void pack_kernel(const float* __restrict__ W0, const float* __restrict__ W1,
                            const float* __restrict__ W2,
                            unsigned short* __restrict__ packW) {
  __shared__ float ldsF[16][257];
  const int s = blockIdx.x, tid = threadIdx.x;
  const float* W; int KT, kmax, base, kt;
  if (s < 9)       { W = W0; KT = 9;  kmax = 134; base = 0;      kt = s; }
  else if (s < 25) { W = W1; KT = 16; kmax = 256; base = 36864;  kt = s - 9; }
  else             { W = W2; KT = 16; kmax = 256; base = 102400; kt = s - 25; }
  const int k0 = kt * 16;
#pragma unroll
  for (int i = 0; i < 8; ++i) {                 // 512 thr x 8 = 16 x 256 floats
    const int idx = i * 512 + tid;
    const int kl = idx >> 8, col = idx & 255;
    const int kg = k0 + kl;
    ldsF[kl][col] = (kg < kmax) ? W[kg * 256 + col] : 0.0f;   // coalesced rows
  }
  __syncthreads();
  const int g = tid >> 7, t = (tid >> 6) & 1, lane = tid & 63;
  const int col = g * 64 + t * 32 + (lane & 31);
  const int kb = 8 * (lane >> 5);
  unsigned u0 = pk2bf(ldsF[kb + 0][col], ldsF[kb + 1][col]);
  unsigned u1 = pk2bf(ldsF[kb + 2][col], ldsF[kb + 3][col]);
  unsigned u2 = pk2bf(ldsF[kb + 4][col], ldsF[kb + 5][col]);
  unsigned u3 = pk2bf(ldsF[kb + 6][col], ldsF[kb + 7][col]);
  unsigned short* dst = packW + base + g * (KT * 1024) + t * (KT * 512) + kt * 512 + lane * 8;
  i32x4 v = { (int)u0, (int)u1, (int)u2, (int)u3 };
  *(i32x4*)dst = v;
}

// ======================================================================
// New decomposition: wave w owns ALL 256 nodes x cols [32w, 32w+32).
//  - B slice (KT x 512 shorts) lives in 16 bf16x8 registers, loaded ONCE
//    per layer per wave -> weights read once per BLOCK (8x less L2).
//  - Activations h[node][k] live in a block-shared 128KB bf16 LDS buffer,
//    XOR-swizzled per 16B slot: slot' = slot ^ (node&31) (same bijection
//    on write and read -> consistent, conflict-minimal).
//  - Cyclic aggregation (node +-1 with wrap) is fully in-lane across the
//    8 acc tiles + shfl_xor(32) for the q-half boundaries. No inter-wave
//    exchange, no spin flags, no per-wave scratch.
// C/D layout (verified): col = lane&31, row = (reg&3) + 8*(reg>>2) + 4*(lane>>5).
// A layout: row = lane&31 (= node 32nt+c), k = 8*(lane>>5)+j within k-tile.
// ======================================================================

template <int KT>
__device__ __forceinline__ void kloop(const unsigned short* __restrict__ hbuf,
                                      const bf16x8* Bf, const int q, const int c,
                                      f32x16* acc) {
#pragma unroll
  for (int nt = 0; nt < 8; ++nt)
#pragma unroll
    for (int j = 0; j < 16; ++j) acc[nt][j] = 0.f;
#pragma unroll
  for (int kt = 0; kt < KT; ++kt) {
    // A-frag for (nt, kt): 8 bf16 at h[node=32nt+c][16kt+8q ...], swizzled slot
    const unsigned short* base = hbuf + c * 256 + (((2 * kt + q) ^ c) * 8);
    bf16x8 Af[8];
#pragma unroll
    for (int nt = 0; nt < 8; ++nt)
      Af[nt] = *(const bf16x8*)(base + nt * 8192);
#pragma unroll
    for (int nt = 0; nt < 8; ++nt)
      acc[nt] = __builtin_amdgcn_mfma_f32_32x32x16_bf16(Af[nt], Bf[kt], acc[nt], 0, 0, 0);
  }
}

template <int LAYER>
__device__ __forceinline__ void epilogue(f32x16* acc, const int q, const float bias,
                                         unsigned short* __restrict__ hbuf,
                                         const int* rowAddr, float& psum) {
  const float T = 0.33333333333f;
  // cross-tile boundary pre-pass (row 31 of nt <-> row 0 of nt+1, wraps node 255->0):
  // q1 sends acc[nt][15] (row31), q0 sends acc[nt+1][0] (row32).
  // After shfl: q1 lane holds next-of-row31; q0 lane holds prev-of-row0(tile nt+1).
  float c7[8];
#pragma unroll
  for (int nt = 0; nt < 8; ++nt) {
    const float send = q ? acc[nt][15] : acc[(nt + 1) & 7][0];
    c7[nt] = __shfl_xor(send, 32);
  }
#pragma unroll
  for (int nt = 0; nt < 8; ++nt) {
    // internal q-half boundaries k=0..6: rows (4k+3, 4k+4)
    float rk[7];
#pragma unroll
    for (int k = 0; k < 7; ++k) {
      const int lowReg = 4 * (k >> 1) + 3;     // reg of row 4k+3 (owner q = k&1)
      const int upReg  = 4 * ((k + 1) >> 1);   // reg of row 4k+4 (owner q = 1-(k&1))
      const float send = (q == (k & 1)) ? acc[nt][lowReg] : acc[nt][upReg];
      rk[k] = __shfl_xor(send, 32);
    }
#pragma unroll
    for (int r = 0; r < 16; ++r) {
      float prev, next;
      if ((r & 3) > 0) prev = acc[nt][r - 1];
      else {
        const float pq1 = rk[2 * (r >> 2)];
        const float pq0 = (r == 0) ? c7[(nt + 7) & 7] : rk[2 * (r >> 2) - 1];
        prev = q ? pq1 : pq0;
      }
      if ((r & 3) < 3) next = acc[nt][r + 1];
      else {
        const float nq0 = rk[2 * (r >> 2)];
        const float nq1 = (r == 15) ? c7[nt] : rk[2 * (r >> 2) + 1];
        next = q ? nq1 : nq0;
      }
      const float v = (prev + acc[nt][r] + next) * T + bias;
      const float y = silu_f(v);
      if constexpr (LAYER == 2) psum += y;                 // in-register mean pool
      else *(unsigned short*)((char*)hbuf + nt * 16384 + rowAddr[r]) = f2bf(y);
    }
  }
}

// ---------------- main fused kernel: 1 block = 1 graph, 8 waves x 32 cols ----------
__global__ __launch_bounds__(512, 2) void poly_kernel(
    const float* __restrict__ x, const float* __restrict__ t,
    const float* __restrict__ tw, const float* __restrict__ tb,
    const unsigned short* __restrict__ packW,
    const float* __restrict__ B0, const float* __restrict__ B1,
    const float* __restrict__ B2, float* __restrict__ out) {
  __shared__ __align__(16) unsigned short hbuf[65536];  // 128 KiB: h[node][256] bf16, swizzled
  __shared__ __align__(16) unsigned short tmpl[160];    // h0 row template (temb + pads)

  const int tid = threadIdx.x;
  const int w = tid >> 6, lane = tid & 63, q = lane >> 5, c = lane & 31;
  const int b = blockIdx.x;

  // ---- fused time MLP: temb = silu(sinemb(t[b]) @ tw + tb) ----
  {
    float* scr = (float*)hbuf;        // reuse h as f32 scratch (overwritten later)
    if (tid < 128) {
      const float tv = t[b];
      const int i = tid & 63;
      const float f = expf(-0.14619588396823767f * (float)i);  // log(1e4)/63
      const float ang = tv * f;
      scr[tid] = (tid < 64) ? sinf(ang) : cosf(ang);
    }
    __syncthreads();
    {
      const int j = tid & 127, p = tid >> 7;   // 4-way k-split over the block
      float a = 0.f;
#pragma unroll 8
      for (int kk = 0; kk < 32; ++kk) a += scr[p * 32 + kk] * tw[(p * 32 + kk) * 128 + j];
      scr[128 + tid] = a;
    }
    __syncthreads();
    if (tid < 128) {
      const float a = tb[tid] + scr[128 + tid] + scr[256 + tid] + scr[384 + tid] + scr[512 + tid];
      tmpl[6 + tid] = f2bf(silu_f(a));
      if (tid < 6)  tmpl[tid] = 0;
      if (tid < 26) tmpl[134 + tid] = 0;   // pad k 134..159 = 0
    }
    __syncthreads();
  }

  // ---- build h0: [x, y, pe(4), temb(128), 0-pad] per node, swizzled slots 0..17 ----
#pragma unroll
  for (int i = 0; i < 9; ++i) {
    const int task = tid + i * 512;            // 4608 = 256 nodes x 18 slots
    const int node = task & 255, slot = task >> 8;
    i32x4 d = *(const i32x4*)(tmpl + slot * 8);
    if (slot == 0) {                           // per-node coords + cycle pos-enc
      const float2 xy = ((const float2*)x)[b * 256 + node];
      const float th = 0.024543692605870074f * (float)node;   // 2*pi/256
      d.x = (int)pk2bf(xy.x, xy.y);
      d.y = (int)pk2bf(sinf(th), cosf(th));
      d.z = (int)pk2bf(sinf(2.f * th), cosf(2.f * th));
    }
    *(i32x4*)(hbuf + node * 256 + ((slot ^ (node & 31)) * 8)) = d;
  }

  // per-lane h'-write byte addresses (row = node&31 is compile-time per reg)
  int rowAddr[16];
  const int slotW = 4 * w + (c >> 3), offW = (c & 7) * 2;    // k-index = 32w+c
#pragma unroll
  for (int r = 0; r < 16; ++r) {
    const int row = (r & 3) + 8 * (r >> 2) + 4 * q;
    rowAddr[r] = row * 512 + ((slotW ^ row) * 16) + offW;
  }

  // B slices: wave w <-> group g=w>>1, tile t=w&1 (cols 32w..32w+31)
  const unsigned short* pL0 = packW + (w >> 1) * (9 * 1024) + (w & 1) * (9 * 512);
  const unsigned short* pL1 = packW + 36864 + (w >> 1) * (16 * 1024) + (w & 1) * (16 * 512);
  const unsigned short* pL2 = packW + 102400 + (w >> 1) * (16 * 1024) + (w & 1) * (16 * 512);
  bf16x8 Bf[16];
#pragma unroll
  for (int kt = 0; kt < 9; ++kt) Bf[kt] = *(const bf16x8*)(pL0 + kt * 512 + lane * 8);
  const float bias0 = B0[w * 32 + c], bias1 = B1[w * 32 + c], bias2 = B2[w * 32 + c];
  __syncthreads();   // h0 ready

  f32x16 acc[8];
  float psum = 0.f;

  // ---- layer 0 (K=144 padded) ----
  kloop<9>(hbuf, Bf, q, c, acc);
  __syncthreads();   // all reads of h0 done
#pragma unroll
  for (int kt = 0; kt < 16; ++kt) Bf[kt] = *(const bf16x8*)(pL1 + kt * 512 + lane * 8);
  epilogue<0>(acc, q, bias0, hbuf, rowAddr, psum);   // writes h1
  __syncthreads();   // h1 ready

  // ---- layer 1 ----
  kloop<16>(hbuf, Bf, q, c, acc);
  __syncthreads();   // all reads of h1 done
#pragma unroll
  for (int kt = 0; kt < 16; ++kt) Bf[kt] = *(const bf16x8*)(pL2 + kt * 512 + lane * 8);
  epilogue<1>(acc, q, bias1, hbuf, rowAddr, psum);   // writes h2
  __syncthreads();   // h2 ready

  // ---- layer 2 + in-register mean pool ----
  kloop<16>(hbuf, Bf, q, c, acc);
  epilogue<2>(acc, q, bias2, hbuf, rowAddr, psum);

  const float s2 = psum + __shfl_xor(psum, 32);
  if (q == 0) out[b * 256 + w * 32 + c] = s2 * (1.0f / 256.0f);
}

// ---------------- launch ----------------
extern "C" void kernel_launch(void* const* d_in, const int* in_sizes, int n_in,
                              void* d_out, int out_size, void* d_ws, size_t ws_size,
                              hipStream_t stream) {
  const float* x  = (const float*)d_in[0];
  const float* t  = (const float*)d_in[1];
  const float* tw = (const float*)d_in[2];
  const float* tb = (const float*)d_in[3];
  const float* W0 = (const float*)d_in[4];
  const float* b0 = (const float*)d_in[5];
  const float* W1 = (const float*)d_in[6];
  const float* b1 = (const float*)d_in[7];
  const float* W2 = (const float*)d_in[8];
  const float* b2 = (const float*)d_in[9];

  unsigned short* packW = (unsigned short*)d_ws;   // 167936 shorts
  float* out = (float*)d_out;

  pack_kernel<<<41, 512, 0, stream>>>(W0, W1, W2, packW);
  poly_kernel<<<1024, 512, 0, stream>>>(x, t, tw, tb, packW, b0, b1, b2, out);
}

// Round 3
// 251.860 us; speedup vs baseline: 2.8229x; 2.8229x over previous
//
#include <hip/hip_runtime.h>
#include <cstdint>

typedef __attribute__((ext_vector_type(8)))  short bf16x8;   // 8 x bf16 (4 VGPR)
typedef __attribute__((ext_vector_type(16))) float f32x16;   // MFMA 32x32 acc
typedef __attribute__((ext_vector_type(4)))  int   i32x4;

__device__ __forceinline__ unsigned short f2bf(float x) {    // RNE fp32->bf16
  unsigned u = __float_as_uint(x);
  u += 0x7fffu + ((u >> 16) & 1u);
  return (unsigned short)(u >> 16);
}
__device__ __forceinline__ unsigned pk2bf(float lo, float hi) {
#if defined(__has_builtin)
#if __has_builtin(__builtin_amdgcn_cvt_pk_bf16_f32)
  auto v = __builtin_amdgcn_cvt_pk_bf16_f32(lo, hi);
  unsigned u; __builtin_memcpy(&u, &v, 4); return u;
#else
  return ((unsigned)f2bf(hi) << 16) | (unsigned)f2bf(lo);
#endif
#else
  return ((unsigned)f2bf(hi) << 16) | (unsigned)f2bf(lo);
#endif
}
__device__ __forceinline__ float silu_f(float v) {
  return v * __builtin_amdgcn_rcpf(1.0f + __expf(-v));
}

// ---- pack W0/W1/W2 into MFMA B-frag order via LDS transpose (coalesced R+W).
// dest layout: [layer][g(64 cols)][t(32-col tile)][kt][lane][8], K0 padded 134->144.
__global__ void pack_kernel(const float* __restrict__ W0, const float* __restrict__ W1,
                            const float* __restrict__ W2,
                            unsigned short* __restrict__ packW) {
  __shared__ float ldsF[16][257];
  const int s = blockIdx.x, tid = threadIdx.x;
  const float* W; int KT, kmax, base, kt;
  if (s < 9)       { W = W0; KT = 9;  kmax = 134; base = 0;      kt = s; }
  else if (s < 25) { W = W1; KT = 16; kmax = 256; base = 36864;  kt = s - 9; }
  else             { W = W2; KT = 16; kmax = 256; base = 102400; kt = s - 25; }
  const int k0 = kt * 16;
#pragma unroll
  for (int i = 0; i < 8; ++i) {                 // 512 thr x 8 = 16 x 256 floats
    const int idx = i * 512 + tid;
    const int kl = idx >> 8, col = idx & 255;
    const int kg = k0 + kl;
    ldsF[kl][col] = (kg < kmax) ? W[kg * 256 + col] : 0.0f;   // coalesced rows
  }
  __syncthreads();
  const int g = tid >> 7, t = (tid >> 6) & 1, lane = tid & 63;
  const int col = g * 64 + t * 32 + (lane & 31);
  const int kb = 8 * (lane >> 5);
  unsigned u0 = pk2bf(ldsF[kb + 0][col], ldsF[kb + 1][col]);
  unsigned u1 = pk2bf(ldsF[kb + 2][col], ldsF[kb + 3][col]);
  unsigned u2 = pk2bf(ldsF[kb + 4][col], ldsF[kb + 5][col]);
  unsigned u3 = pk2bf(ldsF[kb + 6][col], ldsF[kb + 7][col]);
  unsigned short* dst = packW + base + g * (KT * 1024) + t * (KT * 512) + kt * 512 + lane * 8;
  i32x4 v = { (int)u0, (int)u1, (int)u2, (int)u3 };
  *(i32x4*)dst = v;
}

// ======================================================================
// Decomposition: wave w owns ALL 256 nodes x cols [32w, 32w+32), processed
// in TWO node-chunks of 128 (acc[4] = 64 VGPR, not acc[8] = 128 -> no spills).
//  - B slice in 64 VGPRs, loaded once per layer per wave.
//  - h[256][256] bf16 in 128 KB LDS, 16B-slot XOR swizzle (slot ^= node&31).
//  - Cross-chunk cyclic boundary = 2 saved scalars/lane + shfl_xor(32).
// C/D layout: col = lane&31, row = (reg&3) + 8*(reg>>2) + 4*(lane>>5).
// ======================================================================

template <int KT>
__device__ __forceinline__ void kloop4(const unsigned short* __restrict__ hbuf,
                                       const bf16x8* Bf, const int q, const int c,
                                       const int chunk, f32x16* acc) {
#pragma unroll
  for (int nt = 0; nt < 4; ++nt)
#pragma unroll
    for (int j = 0; j < 16; ++j) acc[nt][j] = 0.f;
  const unsigned short* hb = hbuf + chunk * 32768;      // 4 tiles x 8192 shorts
#pragma unroll
  for (int kt = 0; kt < KT; ++kt) {
    const unsigned short* base = hb + c * 256 + (((2 * kt + q) ^ c) * 8);
    bf16x8 Af[4];
#pragma unroll
    for (int nt = 0; nt < 4; ++nt)
      Af[nt] = *(const bf16x8*)(base + nt * 8192);
#pragma unroll
    for (int nt = 0; nt < 4; ++nt)
      acc[nt] = __builtin_amdgcn_mfma_f32_32x32x16_bf16(Af[nt], Bf[kt], acc[nt], 0, 0, 0);
  }
}

// Epilogue over one 4-tile chunk. CHUNK==0 defers nodes 0 and 127 (ext unused);
// CHUNK==1 uses ext as prev-of-row128 (q0) / next-of-row255 (q1).
template <int LAYER, int CHUNK>
__device__ __forceinline__ void epi4(const f32x16* acc, const int q, const float bias,
                                     unsigned short* __restrict__ hbuf,
                                     const int* rowAddr, float& psum, const float ext) {
  const float T = 0.33333333333f;
  float bsh[3];                       // tile k <-> k+1 boundaries within chunk
#pragma unroll
  for (int k = 0; k < 3; ++k) {
    const float send = q ? acc[k][15] : acc[k + 1][0];
    bsh[k] = __shfl_xor(send, 32);    // q0 gets prev-of-tile(k+1)row0; q1 gets next-of-tile(k)row31
  }
#pragma unroll
  for (int nt = 0; nt < 4; ++nt) {
    float rk[7];                      // internal q-half boundaries rows (4k+3,4k+4)
#pragma unroll
    for (int k = 0; k < 7; ++k) {
      const int lowReg = 4 * (k >> 1) + 3;
      const int upReg  = 4 * ((k + 1) >> 1);
      const float send = (q == (k & 1)) ? acc[nt][lowReg] : acc[nt][upReg];
      rk[k] = __shfl_xor(send, 32);
    }
#pragma unroll
    for (int r = 0; r < 16; ++r) {
      float prev, next;
      if ((r & 3) > 0) prev = acc[nt][r - 1];
      else {
        const float pq1 = rk[2 * (r >> 2)];
        float pq0;
        if (r == 0) pq0 = (nt == 0) ? ext : bsh[nt - 1];
        else        pq0 = rk[2 * (r >> 2) - 1];
        prev = q ? pq1 : pq0;
      }
      if ((r & 3) < 3) next = acc[nt][r + 1];
      else {
        const float nq0 = rk[2 * (r >> 2)];
        float nq1;
        if (r == 15) nq1 = (nt == 3) ? ext : bsh[nt];
        else         nq1 = rk[2 * (r >> 2) + 1];
        next = q ? nq1 : nq0;
      }
      const float v = (prev + acc[nt][r] + next) * T + bias;
      const float y = silu_f(v);
      const bool skip = (CHUNK == 0) &&
          ((nt == 0 && r == 0 && q == 0) || (nt == 3 && r == 15 && q == 1));
      if constexpr (LAYER == 2) { if (!skip) psum += y; }
      else {
        if (!skip)
          *(unsigned short*)((char*)hbuf + (CHUNK * 4 + nt) * 16384 + rowAddr[r]) = f2bf(y);
      }
    }
  }
}

template <int KT, int LAYER>
__device__ __forceinline__ void do_layer(unsigned short* __restrict__ hbuf,
                                         bf16x8* Bf, const unsigned short* pNext,
                                         const int q, const int c, const int lane,
                                         const float bias, const int* rowAddr,
                                         float& psum) {
  const float T = 0.33333333333f;
  f32x16 acc[4];
  // ---- chunk 0 (nodes 0..127): reads h rows 0..127 only ----
  kloop4<KT>(hbuf, Bf, q, c, 0, acc);
  const float sA = q ? acc[3][14] : acc[0][0];   // s[126] | s[0]
  const float sB = q ? acc[3][15] : acc[0][1];   // s[127] | s[1]
  if constexpr (LAYER != 2) __syncthreads();     // all chunk-0 reads done
  epi4<LAYER, 0>(acc, q, bias, hbuf, rowAddr, psum, 0.f);  // writes h' rows 1..126
  // ---- chunk 1 (nodes 128..255): reads h rows 128..255 only ----
  kloop4<KT>(hbuf, Bf, q, c, 1, acc);
  {  // deferred nodes 0 / 127: need s[255] (q1 acc[3][15]) / s[128] (q0 acc[0][0])
    const float send = q ? acc[3][15] : acc[0][0];
    const float recv = __shfl_xor(send, 32);     // q0: s[255], q1: s[128]
    const float y = silu_f((sA + sB + recv) * T + bias);
    if constexpr (LAYER == 2) psum += y;
    else {
      const int addr = q ? (3 * 16384 + rowAddr[15]) : rowAddr[0];
      *(unsigned short*)((char*)hbuf + addr) = f2bf(y);
    }
  }
  if constexpr (LAYER != 2) {
#pragma unroll
    for (int kt = 0; kt < 16; ++kt)              // preload next layer's B slice
      Bf[kt] = *(const bf16x8*)(pNext + kt * 512 + lane * 8);
    __syncthreads();                             // all chunk-1 reads done
  }
  const float ext1 = __shfl_xor(q ? sB : sA, 32);  // q0: s[127], q1: s[0]
  epi4<LAYER, 1>(acc, q, bias, hbuf, rowAddr, psum, ext1);  // writes h' rows 128..255
  if constexpr (LAYER != 2) __syncthreads();     // h' complete
}

// ---------------- main fused kernel: 1 block = 1 graph, 8 waves x 32 cols ----------
__global__ __launch_bounds__(512, 2) void poly_kernel(
    const float* __restrict__ x, const float* __restrict__ t,
    const float* __restrict__ tw, const float* __restrict__ tb,
    const unsigned short* __restrict__ packW,
    const float* __restrict__ B0, const float* __restrict__ B1,
    const float* __restrict__ B2, float* __restrict__ out) {
  __shared__ __align__(16) unsigned short hbuf[65536];  // 128 KiB: h[node][256] bf16, swizzled
  __shared__ __align__(16) unsigned short tmpl[160];    // h0 row template (temb + pads)

  const int tid = threadIdx.x;
  const int w = tid >> 6, lane = tid & 63, q = lane >> 5, c = lane & 31;
  const int b = blockIdx.x;

  // ---- fused time MLP: temb = silu(sinemb(t[b]) @ tw + tb) ----
  {
    float* scr = (float*)hbuf;        // reuse h as f32 scratch (overwritten later)
    if (tid < 128) {
      const float tv = t[b];
      const int i = tid & 63;
      const float f = expf(-0.14619588396823767f * (float)i);  // log(1e4)/63
      const float ang = tv * f;
      scr[tid] = (tid < 64) ? sinf(ang) : cosf(ang);
    }
    __syncthreads();
    {
      const int j = tid & 127, p = tid >> 7;   // 4-way k-split over the block
      float a = 0.f;
#pragma unroll 8
      for (int kk = 0; kk < 32; ++kk) a += scr[p * 32 + kk] * tw[(p * 32 + kk) * 128 + j];
      scr[128 + tid] = a;
    }
    __syncthreads();
    if (tid < 128) {
      const float a = tb[tid] + scr[128 + tid] + scr[256 + tid] + scr[384 + tid] + scr[512 + tid];
      tmpl[6 + tid] = f2bf(silu_f(a));
      if (tid < 6)  tmpl[tid] = 0;
      if (tid < 26) tmpl[134 + tid] = 0;   // pad k 134..159 = 0
    }
    __syncthreads();
  }

  // ---- build h0: [x, y, pe(4), temb(128), 0-pad] per node, swizzled slots 0..17 ----
#pragma unroll
  for (int i = 0; i < 9; ++i) {
    const int task = tid + i * 512;            // 4608 = 256 nodes x 18 slots
    const int node = task & 255, slot = task >> 8;
    i32x4 d = *(const i32x4*)(tmpl + slot * 8);
    if (slot == 0) {                           // per-node coords + cycle pos-enc
      const float2 xy = ((const float2*)x)[b * 256 + node];
      const float th = 0.024543692605870074f * (float)node;   // 2*pi/256
      d.x = (int)pk2bf(xy.x, xy.y);
      d.y = (int)pk2bf(sinf(th), cosf(th));
      d.z = (int)pk2bf(sinf(2.f * th), cosf(2.f * th));
    }
    *(i32x4*)(hbuf + node * 256 + ((slot ^ (node & 31)) * 8)) = d;
  }

  // per-lane h'-write byte addresses (row depends on q; r is compile-time)
  int rowAddr[16];
  const int slotW = 4 * w + (c >> 3), offW = (c & 7) * 2;    // k-index = 32w+c
#pragma unroll
  for (int r = 0; r < 16; ++r) {
    const int row = (r & 3) + 8 * (r >> 2) + 4 * q;
    rowAddr[r] = row * 512 + ((slotW ^ row) * 16) + offW;
  }

  // B slices: wave w <-> group g=w>>1, tile t=w&1 (cols 32w..32w+31)
  const unsigned short* pL0 = packW + (w >> 1) * (9 * 1024) + (w & 1) * (9 * 512);
  const unsigned short* pL1 = packW + 36864 + (w >> 1) * (16 * 1024) + (w & 1) * (16 * 512);
  const unsigned short* pL2 = packW + 102400 + (w >> 1) * (16 * 1024) + (w & 1) * (16 * 512);
  bf16x8 Bf[16];
#pragma unroll
  for (int kt = 0; kt < 9; ++kt) Bf[kt] = *(const bf16x8*)(pL0 + kt * 512 + lane * 8);
  const float bias0 = B0[w * 32 + c], bias1 = B1[w * 32 + c], bias2 = B2[w * 32 + c];
  __syncthreads();   // h0 ready

  float psum = 0.f;
  do_layer< 9, 0>(hbuf, Bf, pL1, q, c, lane, bias0, rowAddr, psum);
  do_layer<16, 1>(hbuf, Bf, pL2, q, c, lane, bias1, rowAddr, psum);
  do_layer<16, 2>(hbuf, Bf, nullptr, q, c, lane, bias2, rowAddr, psum);

  const float s2 = psum + __shfl_xor(psum, 32);
  if (q == 0) out[b * 256 + w * 32 + c] = s2 * (1.0f / 256.0f);
}

// ---------------- launch ----------------
extern "C" void kernel_launch(void* const* d_in, const int* in_sizes, int n_in,
                              void* d_out, int out_size, void* d_ws, size_t ws_size,
                              hipStream_t stream) {
  const float* x  = (const float*)d_in[0];
  const float* t  = (const float*)d_in[1];
  const float* tw = (const float*)d_in[2];
  const float* tb = (const float*)d_in[3];
  const float* W0 = (const float*)d_in[4];
  const float* b0 = (const float*)d_in[5];
  const float* W1 = (const float*)d_in[6];
  const float* b1 = (const float*)d_in[7];
  const float* W2 = (const float*)d_in[8];
  const float* b2 = (const float*)d_in[9];

  unsigned short* packW = (unsigned short*)d_ws;   // 167936 shorts
  float* out = (float*)d_out;

  pack_kernel<<<41, 512, 0, stream>>>(W0, W1, W2, packW);
  poly_kernel<<<1024, 512, 0, stream>>>(x, t, tw, tb, packW, b0, b1, b2, out);
}